// Round 1
// baseline (52.732 us; speedup 1.0000x reference)
//
#include <hip/hip_runtime.h>
#include <math.h>

// Problem constants (from reference setup_inputs)
#define BB 512
#define TT 8000
#define SS 3
#define CH 4            // T-chunks per batch
#define TC (TT/CH)      // 2000 t per chunk
#define NV (TC/4)       // 500 vec4 items per chunk
#define NACC 13         // 3 SP + 9 XT + 1 msum

__device__ __forceinline__ double waveReduce(double v) {
    #pragma unroll
    for (int o = 32; o > 0; o >>= 1) v += __shfl_down(v, o, 64);
    return v;
}

// Kernel 1: per (b, chunk) partial sums of the 13 reductions, in double.
__global__ __launch_bounds__(256) void pit_partial(
        const float* __restrict__ pred,
        const float* __restrict__ tgt,
        const float* __restrict__ mask,
        double* __restrict__ partials) {
    int blk = blockIdx.x;
    int b = blk / CH, c = blk % CH;
    int tbase = c * TC;
    const float* pp = pred + ((size_t)b * TT + tbase) * 3;
    const float* tp = tgt  + ((size_t)b * TT + tbase) * 3;
    const float* mp = mask + (size_t)b * TT + tbase;

    double acc[NACC];
    #pragma unroll
    for (int k = 0; k < NACC; k++) acc[k] = 0.0;

    for (int item = threadIdx.x; item < NV; item += 256) {
        const float4* p4 = (const float4*)(pp + (size_t)item * 12);
        float4 pa = p4[0], pb = p4[1], pc = p4[2];
        const float4* t4 = (const float4*)(tp + (size_t)item * 12);
        float4 ta = t4[0], tb = t4[1], tc = t4[2];
        float4 mm = *(const float4*)(mp + (size_t)item * 4);

        float px[4][3] = {{pa.x,pa.y,pa.z},{pa.w,pb.x,pb.y},
                          {pb.z,pb.w,pc.x},{pc.y,pc.z,pc.w}};
        float tx[4][3] = {{ta.x,ta.y,ta.z},{ta.w,tb.x,tb.y},
                          {tb.z,tb.w,tc.x},{tc.y,tc.z,tc.w}};
        float mv[4] = {mm.x, mm.y, mm.z, mm.w};

        #pragma unroll
        for (int u = 0; u < 4; u++) {
            float m = mv[u];
            acc[12] += (double)m;
            #pragma unroll
            for (int i = 0; i < 3; i++) {
                float x = px[u][i];
                // softplus(x) = max(x,0) + log1p(exp(-|x|))
                float sp = fmaxf(x, 0.0f) + log1pf(__expf(-fabsf(x)));
                acc[i] += (double)(m * sp);
                #pragma unroll
                for (int j = 0; j < 3; j++) {
                    acc[3 + i*3 + j] += (double)(m * x * tx[u][j]);
                }
            }
        }
    }

    // Block reduction: wave shuffle -> LDS across 4 waves -> thread 0 writes.
    __shared__ double sdata[4][NACC];
    int lane = threadIdx.x & 63, wave = threadIdx.x >> 6;
    #pragma unroll
    for (int k = 0; k < NACC; k++) {
        double v = waveReduce(acc[k]);
        if (lane == 0) sdata[wave][k] = v;
    }
    __syncthreads();
    if (threadIdx.x == 0) {
        #pragma unroll
        for (int k = 0; k < NACC; k++) {
            double s = sdata[0][k] + sdata[1][k] + sdata[2][k] + sdata[3][k];
            partials[(size_t)blk * NACC + k] = s;
        }
    }
}

// Kernel 2: per-b finalize — sum chunks, build cost, scan 6 perms, write idx.
__global__ __launch_bounds__(64) void pit_finalize(
        const double* __restrict__ partials,
        double* __restrict__ bestv,
        float* __restrict__ out) {
    int b = blockIdx.x * 64 + threadIdx.x;
    if (b >= BB) return;
    double acc[NACC];
    #pragma unroll
    for (int k = 0; k < NACC; k++) {
        double s = 0.0;
        for (int c = 0; c < CH; c++)
            s += partials[((size_t)b * CH + c) * NACC + k];
        acc[k] = s;
    }
    double msum = acc[12] + 1e-14;
    double cost[3][3];
    #pragma unroll
    for (int i = 0; i < 3; i++)
        #pragma unroll
        for (int j = 0; j < 3; j++)
            cost[i][j] = (acc[i] - acc[3 + i*3 + j]) / msum;

    const int perms[6][3] = {{0,1,2},{0,2,1},{1,0,2},{1,2,0},{2,0,1},{2,1,0}};
    double best = 1e300; int bidx = 0;
    #pragma unroll
    for (int p = 0; p < 6; p++) {
        double v = (cost[0][perms[p][0]] + cost[1][perms[p][1]] +
                    cost[2][perms[p][2]]) / 3.0;
        if (v < best) { best = v; bidx = p; }
    }
    bestv[b] = best;
    out[1 + b] = (float)bidx;
}

// Kernel 3: mean of best_val over B -> out[0].
__global__ __launch_bounds__(256) void pit_mean(
        const double* __restrict__ bestv, float* __restrict__ out) {
    __shared__ double sd[4];
    double v = 0.0;
    for (int b = threadIdx.x; b < BB; b += 256) v += bestv[b];
    int lane = threadIdx.x & 63, wave = threadIdx.x >> 6;
    v = waveReduce(v);
    if (lane == 0) sd[wave] = v;
    __syncthreads();
    if (threadIdx.x == 0) {
        double s = sd[0] + sd[1] + sd[2] + sd[3];
        out[0] = (float)(s / (double)BB);
    }
}

extern "C" void kernel_launch(void* const* d_in, const int* in_sizes, int n_in,
                              void* d_out, int out_size, void* d_ws, size_t ws_size,
                              hipStream_t stream) {
    const float* pred = (const float*)d_in[0];
    const float* tgt  = (const float*)d_in[1];
    const float* mask = (const float*)d_in[2];
    float* out = (float*)d_out;

    double* partials = (double*)d_ws;                     // BB*CH*NACC doubles
    double* bestv    = partials + (size_t)BB * CH * NACC; // BB doubles

    pit_partial<<<BB * CH, 256, 0, stream>>>(pred, tgt, mask, partials);
    pit_finalize<<<(BB + 63) / 64, 64, 0, stream>>>(partials, bestv, out);
    pit_mean<<<1, 256, 0, stream>>>(bestv, out);
}

// Round 2
// 34.537 us; speedup vs baseline: 1.5268x; 1.5268x over previous
//
#include <hip/hip_runtime.h>
#include <math.h>

// Problem constants (from reference setup_inputs)
#define BB 512
#define TT 8000
#define SS 3
#define CH 4            // T-chunks per batch
#define TC (TT/CH)      // 2000 t per chunk
#define NV (TC/4)       // 500 vec4 items per chunk
#define NACC 13         // 3 SP + 9 XT + 1 msum

__device__ __forceinline__ double waveReduceD(double v) {
    #pragma unroll
    for (int o = 32; o > 0; o >>= 1) v += __shfl_down(v, o, 64);
    return v;
}

// Kernel 1: per (b, chunk) partial sums of the 13 reductions.
// Per-thread accumulation in float (≈8 elements/thread — error ~1e-6 abs),
// cross-thread reduction in double for determinism/precision.
__global__ __launch_bounds__(256) void pit_partial(
        const float* __restrict__ pred,
        const float* __restrict__ tgt,
        const float* __restrict__ mask,
        double* __restrict__ partials) {
    int blk = blockIdx.x;
    int b = blk / CH, c = blk % CH;
    int tbase = c * TC;
    const float* pp = pred + ((size_t)b * TT + tbase) * 3;
    const float* tp = tgt  + ((size_t)b * TT + tbase) * 3;
    const float* mp = mask + (size_t)b * TT + tbase;

    float acc[NACC];
    #pragma unroll
    for (int k = 0; k < NACC; k++) acc[k] = 0.0f;

    for (int item = threadIdx.x; item < NV; item += 256) {
        const float4* p4 = (const float4*)(pp + (size_t)item * 12);
        float4 pa = p4[0], pb = p4[1], pc = p4[2];
        const float4* t4 = (const float4*)(tp + (size_t)item * 12);
        float4 ta = t4[0], tb = t4[1], tc = t4[2];
        float4 mm = *(const float4*)(mp + (size_t)item * 4);

        float px[4][3] = {{pa.x,pa.y,pa.z},{pa.w,pb.x,pb.y},
                          {pb.z,pb.w,pc.x},{pc.y,pc.z,pc.w}};
        float tx[4][3] = {{ta.x,ta.y,ta.z},{ta.w,tb.x,tb.y},
                          {tb.z,tb.w,tc.x},{tc.y,tc.z,tc.w}};
        float mv[4] = {mm.x, mm.y, mm.z, mm.w};

        #pragma unroll
        for (int u = 0; u < 4; u++) {
            float m = mv[u];
            acc[12] += m;
            #pragma unroll
            for (int i = 0; i < 3; i++) {
                float x = px[u][i];
                // softplus(x) = max(x,0) + log(1 + exp(-|x|)) via native
                // v_exp_f32/v_log_f32 (~2 ulp; permutation-invariant term).
                float sp = fmaxf(x, 0.0f) + __logf(1.0f + __expf(-fabsf(x)));
                acc[i] = fmaf(m, sp, acc[i]);
                float mx = m * x;
                #pragma unroll
                for (int j = 0; j < 3; j++) {
                    acc[3 + i*3 + j] = fmaf(mx, tx[u][j], acc[3 + i*3 + j]);
                }
            }
        }
    }

    // Block reduction: wave shuffle (double) -> LDS across 4 waves -> write.
    __shared__ double sdata[4][NACC];
    int lane = threadIdx.x & 63, wave = threadIdx.x >> 6;
    #pragma unroll
    for (int k = 0; k < NACC; k++) {
        double v = waveReduceD((double)acc[k]);
        if (lane == 0) sdata[wave][k] = v;
    }
    __syncthreads();
    if (threadIdx.x == 0) {
        #pragma unroll
        for (int k = 0; k < NACC; k++) {
            double s = sdata[0][k] + sdata[1][k] + sdata[2][k] + sdata[3][k];
            partials[(size_t)blk * NACC + k] = s;
        }
    }
}

// Kernel 2: per-b finalize — sum chunks, build cost, scan 6 perms, write idx.
__global__ __launch_bounds__(64) void pit_finalize(
        const double* __restrict__ partials,
        double* __restrict__ bestv,
        float* __restrict__ out) {
    int b = blockIdx.x * 64 + threadIdx.x;
    if (b >= BB) return;
    double acc[NACC];
    #pragma unroll
    for (int k = 0; k < NACC; k++) {
        double s = 0.0;
        for (int c = 0; c < CH; c++)
            s += partials[((size_t)b * CH + c) * NACC + k];
        acc[k] = s;
    }
    double msum = acc[12] + 1e-14;
    double cost[3][3];
    #pragma unroll
    for (int i = 0; i < 3; i++)
        #pragma unroll
        for (int j = 0; j < 3; j++)
            cost[i][j] = (acc[i] - acc[3 + i*3 + j]) / msum;

    const int perms[6][3] = {{0,1,2},{0,2,1},{1,0,2},{1,2,0},{2,0,1},{2,1,0}};
    double best = 1e300; int bidx = 0;
    #pragma unroll
    for (int p = 0; p < 6; p++) {
        double v = (cost[0][perms[p][0]] + cost[1][perms[p][1]] +
                    cost[2][perms[p][2]]) / 3.0;
        if (v < best) { best = v; bidx = p; }
    }
    bestv[b] = best;
    out[1 + b] = (float)bidx;
}

// Kernel 3: mean of best_val over B -> out[0].
__global__ __launch_bounds__(256) void pit_mean(
        const double* __restrict__ bestv, float* __restrict__ out) {
    __shared__ double sd[4];
    double v = 0.0;
    for (int b = threadIdx.x; b < BB; b += 256) v += bestv[b];
    int lane = threadIdx.x & 63, wave = threadIdx.x >> 6;
    v = waveReduceD(v);
    if (lane == 0) sd[wave] = v;
    __syncthreads();
    if (threadIdx.x == 0) {
        double s = sd[0] + sd[1] + sd[2] + sd[3];
        out[0] = (float)(s / (double)BB);
    }
}

extern "C" void kernel_launch(void* const* d_in, const int* in_sizes, int n_in,
                              void* d_out, int out_size, void* d_ws, size_t ws_size,
                              hipStream_t stream) {
    const float* pred = (const float*)d_in[0];
    const float* tgt  = (const float*)d_in[1];
    const float* mask = (const float*)d_in[2];
    float* out = (float*)d_out;

    double* partials = (double*)d_ws;                     // BB*CH*NACC doubles
    double* bestv    = partials + (size_t)BB * CH * NACC; // BB doubles

    pit_partial<<<BB * CH, 256, 0, stream>>>(pred, tgt, mask, partials);
    pit_finalize<<<(BB + 63) / 64, 64, 0, stream>>>(partials, bestv, out);
    pit_mean<<<1, 256, 0, stream>>>(bestv, out);
}

// Round 3
// 32.255 us; speedup vs baseline: 1.6349x; 1.0708x over previous
//
#include <hip/hip_runtime.h>
#include <math.h>

// Problem constants (from reference setup_inputs)
#define BB 512
#define TT 8000
#define SS 3
#define CH 4            // T-chunks per batch
#define TC (TT/CH)      // 2000 t per chunk
#define NV (TC/4)       // 500 vec4 items (4 t each) per chunk
#define NACC 13         // 3 SP + 9 XT + 1 msum
#define NWAVE 4         // waves per block
#define WPB (BB*CH*NWAVE) // total wave-partials (8192)

__device__ __forceinline__ double waveReduceD(double v) {
    #pragma unroll
    for (int o = 32; o > 0; o >>= 1) v += __shfl_down(v, o, 64);
    return v;
}

__device__ __forceinline__ void accum_elem(float acc[NACC], float m,
                                           float x0, float x1, float x2,
                                           float t0, float t1, float t2) {
    acc[12] += m;
    float x[3] = {x0, x1, x2};
    float t[3] = {t0, t1, t2};
    #pragma unroll
    for (int i = 0; i < 3; i++) {
        float xi = x[i];
        float sp = fmaxf(xi, 0.0f) + __logf(1.0f + __expf(-fabsf(xi)));
        acc[i] = fmaf(m, sp, acc[i]);
        float mx = m * xi;
        #pragma unroll
        for (int j = 0; j < 3; j++)
            acc[3 + i*3 + j] = fmaf(mx, t[j], acc[3 + i*3 + j]);
    }
}

__device__ __forceinline__ void accum_item(float acc[NACC],
                                           float4 pa, float4 pb, float4 pc,
                                           float4 ta, float4 tb, float4 tc,
                                           float4 mm) {
    accum_elem(acc, mm.x, pa.x, pa.y, pa.z, ta.x, ta.y, ta.z);
    accum_elem(acc, mm.y, pa.w, pb.x, pb.y, ta.w, tb.x, tb.y);
    accum_elem(acc, mm.z, pb.z, pb.w, pc.x, tb.z, tb.w, tc.x);
    accum_elem(acc, mm.w, pc.y, pc.z, pc.w, tc.y, tc.z, tc.w);
}

// Kernel 1: per (b, chunk) wave-level partial sums of the 13 reductions.
// Exactly 2 items per thread, all 14 float4 loads issued before compute.
// Wave butterfly reduce in f32; lane 0 writes 13 floats. No LDS, no barrier.
__global__ __launch_bounds__(256) void pit_partial(
        const float* __restrict__ pred,
        const float* __restrict__ tgt,
        const float* __restrict__ mask,
        float* __restrict__ wpart) {
    int blk = blockIdx.x;
    int b = blk >> 2, c = blk & 3;
    int tbase = c * TC;
    const float* pp = pred + ((size_t)b * TT + tbase) * 3;
    const float* tp = tgt  + ((size_t)b * TT + tbase) * 3;
    const float* mp = mask + (size_t)b * TT + tbase;

    int tid = threadIdx.x;
    int i0 = tid;                       // always < NV
    int i1 = tid + 256;
    bool v1 = (i1 < NV);
    int i1c = v1 ? i1 : (NV - 1);       // clamp: data is finite, masked out

    // Issue all loads up front (14 independent float4 loads).
    const float4* p40 = (const float4*)(pp + (size_t)i0 * 12);
    const float4* t40 = (const float4*)(tp + (size_t)i0 * 12);
    float4 pa0 = p40[0], pb0 = p40[1], pc0 = p40[2];
    float4 ta0 = t40[0], tb0 = t40[1], tc0 = t40[2];
    float4 mm0 = *(const float4*)(mp + (size_t)i0 * 4);

    const float4* p41 = (const float4*)(pp + (size_t)i1c * 12);
    const float4* t41 = (const float4*)(tp + (size_t)i1c * 12);
    float4 pa1 = p41[0], pb1 = p41[1], pc1 = p41[2];
    float4 ta1 = t41[0], tb1 = t41[1], tc1 = t41[2];
    float4 mm1 = *(const float4*)(mp + (size_t)i1c * 4);
    if (!v1) { mm1.x = mm1.y = mm1.z = mm1.w = 0.0f; }

    float acc[NACC];
    #pragma unroll
    for (int k = 0; k < NACC; k++) acc[k] = 0.0f;

    accum_item(acc, pa0, pb0, pc0, ta0, tb0, tc0, mm0);
    accum_item(acc, pa1, pb1, pc1, ta1, tb1, tc1, mm1);

    // f32 butterfly reduce across the wave (all lanes get the sum).
    #pragma unroll
    for (int k = 0; k < NACC; k++) {
        float v = acc[k];
        #pragma unroll
        for (int o = 32; o > 0; o >>= 1) v += __shfl_xor(v, o, 64);
        acc[k] = v;
    }

    int lane = tid & 63, wave = tid >> 6;
    if (lane == 0) {
        float* dst = wpart + ((size_t)blk * NWAVE + wave) * NACC;
        #pragma unroll
        for (int k = 0; k < NACC; k++) dst[k] = acc[k];
    }
}

// Kernel 2: per-b finalize — sum the 16 wave-partials (double), build cost,
// scan 6 perms, write best idx.
__global__ __launch_bounds__(64) void pit_finalize(
        const float* __restrict__ wpart,
        double* __restrict__ bestv,
        float* __restrict__ out) {
    int b = blockIdx.x * 64 + threadIdx.x;
    if (b >= BB) return;
    const float* p = wpart + (size_t)b * (CH * NWAVE * NACC); // 208 floats
    double acc[NACC];
    #pragma unroll
    for (int k = 0; k < NACC; k++) acc[k] = 0.0;
    #pragma unroll
    for (int g = 0; g < CH * NWAVE; g++)
        #pragma unroll
        for (int k = 0; k < NACC; k++)
            acc[k] += (double)p[g * NACC + k];

    double msum = acc[12] + 1e-14;
    double cost[3][3];
    #pragma unroll
    for (int i = 0; i < 3; i++)
        #pragma unroll
        for (int j = 0; j < 3; j++)
            cost[i][j] = (acc[i] - acc[3 + i*3 + j]) / msum;

    const int perms[6][3] = {{0,1,2},{0,2,1},{1,0,2},{1,2,0},{2,0,1},{2,1,0}};
    double best = 1e300; int bidx = 0;
    #pragma unroll
    for (int p6 = 0; p6 < 6; p6++) {
        double v = (cost[0][perms[p6][0]] + cost[1][perms[p6][1]] +
                    cost[2][perms[p6][2]]) / 3.0;
        if (v < best) { best = v; bidx = p6; }
    }
    bestv[b] = best;
    out[1 + b] = (float)bidx;
}

// Kernel 3: mean of best_val over B -> out[0].
__global__ __launch_bounds__(256) void pit_mean(
        const double* __restrict__ bestv, float* __restrict__ out) {
    __shared__ double sd[4];
    double v = 0.0;
    for (int b = threadIdx.x; b < BB; b += 256) v += bestv[b];
    int lane = threadIdx.x & 63, wave = threadIdx.x >> 6;
    v = waveReduceD(v);
    if (lane == 0) sd[wave] = v;
    __syncthreads();
    if (threadIdx.x == 0) {
        double s = sd[0] + sd[1] + sd[2] + sd[3];
        out[0] = (float)(s / (double)BB);
    }
}

extern "C" void kernel_launch(void* const* d_in, const int* in_sizes, int n_in,
                              void* d_out, int out_size, void* d_ws, size_t ws_size,
                              hipStream_t stream) {
    const float* pred = (const float*)d_in[0];
    const float* tgt  = (const float*)d_in[1];
    const float* mask = (const float*)d_in[2];
    float* out = (float*)d_out;

    float* wpart  = (float*)d_ws;                       // WPB*NACC floats
    double* bestv = (double*)((char*)d_ws + ((WPB * NACC * 4 + 255) & ~255));

    pit_partial<<<BB * CH, 256, 0, stream>>>(pred, tgt, mask, wpart);
    pit_finalize<<<(BB + 63) / 64, 64, 0, stream>>>(wpart, bestv, out);
    pit_mean<<<1, 256, 0, stream>>>(bestv, out);
}

// Round 4
// 32.212 us; speedup vs baseline: 1.6370x; 1.0013x over previous
//
#include <hip/hip_runtime.h>
#include <math.h>

// Problem constants
#define BB 512
#define TT 8000
#define TILE 1024            // elements per tile (full tiles)
#define NTILE 7              // full tiles staged via global_load_lds
#define TAILB (NTILE*TILE)   // 7168
#define TAILN (TT-TAILB)     // 832 tail elements
#define TAILIT (TAILN/4)     // 208 tail items (4 elems each)
#define NACC 13              // 3 SP + 9 XT + 1 msum

// Per-wave LDS slice: per buffer {pred 768f, tgt 768f, mask 256f} = 1792 floats.
// wave slice = 2 buffers = 3584 floats. 4 waves = 14336 floats = 56 KB.
#define BUF_F 1792
#define SLICE_F (2*BUF_F)

__device__ __forceinline__ void ld16(const float4* g, float* l) {
    __builtin_amdgcn_global_load_lds(
        (const __attribute__((address_space(1))) void*)g,
        (__attribute__((address_space(3))) void*)l, 16, 0, 0);
}

#define WAIT_VM7() { asm volatile("s_waitcnt vmcnt(7)" ::: "memory"); \
                     __builtin_amdgcn_sched_barrier(0); }
#define WAIT_VM0() { asm volatile("s_waitcnt vmcnt(0)" ::: "memory"); \
                     __builtin_amdgcn_sched_barrier(0); }

__device__ __forceinline__ void accum_elem(float acc[NACC], float m,
                                           float x0, float x1, float x2,
                                           float t0, float t1, float t2) {
    acc[12] += m;
    float x[3] = {x0, x1, x2};
    float t[3] = {t0, t1, t2};
    #pragma unroll
    for (int i = 0; i < 3; i++) {
        float xi = x[i];
        float sp = fmaxf(xi, 0.0f) + __logf(1.0f + __expf(-fabsf(xi)));
        acc[i] = fmaf(m, sp, acc[i]);
        float mx = m * xi;
        #pragma unroll
        for (int j = 0; j < 3; j++)
            acc[3 + i*3 + j] = fmaf(mx, t[j], acc[3 + i*3 + j]);
    }
}

__device__ __forceinline__ void accum_item(float acc[NACC],
                                           float4 pa, float4 pb, float4 pc,
                                           float4 ta, float4 tb, float4 tc,
                                           float4 mm) {
    accum_elem(acc, mm.x, pa.x, pa.y, pa.z, ta.x, ta.y, ta.z);
    accum_elem(acc, mm.y, pa.w, pb.x, pb.y, ta.w, tb.x, tb.y);
    accum_elem(acc, mm.z, pb.z, pb.w, pc.x, tb.z, tb.w, tc.x);
    accum_elem(acc, mm.w, pc.y, pc.z, pc.w, tc.y, tc.z, tc.w);
}

// One block per batch. Per-wave barrier-free double-buffered pipeline:
// wave w owns elements [u*1024 + w*256, +256) of each tile u.
__global__ __launch_bounds__(256) void pit_batch(
        const float* __restrict__ pred,
        const float* __restrict__ tgt,
        const float* __restrict__ mask,
        double* __restrict__ bestv,
        float* __restrict__ out) {
    __shared__ float lds[4 * SLICE_F];
    __shared__ float red[4][NACC];

    int b = blockIdx.x;
    int tid = threadIdx.x, lane = tid & 63, w = tid >> 6;
    const float* pb = pred + (size_t)b * TT * 3;
    const float* tb = tgt  + (size_t)b * TT * 3;
    const float* mb = mask + (size_t)b * TT;

    // ---- Tail loads (strided reg path), issued up-front for overlap ----
    int it = tid < TAILIT ? tid : (TAILIT - 1);   // clamp: no divergence
    const float4* tp = (const float4*)(pb + (size_t)(TAILB + 4*it) * 3);
    const float4* tt = (const float4*)(tb + (size_t)(TAILB + 4*it) * 3);
    float4 PA = tp[0], PB = tp[1], PC = tp[2];
    float4 TA = tt[0], TB = tt[1], TC = tt[2];
    float4 MM = *(const float4*)(mb + TAILB + 4*it);

    float* slice = lds + w * SLICE_F;
    const float4* pg4 = (const float4*)pb;
    const float4* tg4 = (const float4*)tb;
    const float4* mg4 = (const float4*)mb;

    // stage(tile u, buf d): 7 dense global_load_lds per wave
    #define STAGE(u, d) { \
        float* base_ = slice + (d) * BUF_F; \
        const float4* p_ = pg4 + (size_t)(u)*768 + w*192 + lane; \
        const float4* t_ = tg4 + (size_t)(u)*768 + w*192 + lane; \
        const float4* m_ = mg4 + (size_t)(u)*256 + w*64  + lane; \
        ld16(p_,       base_); \
        ld16(p_ + 64,  base_ + 256); \
        ld16(p_ + 128, base_ + 512); \
        ld16(t_,       base_ + 768); \
        ld16(t_ + 64,  base_ + 1024); \
        ld16(t_ + 128, base_ + 1280); \
        ld16(m_,       base_ + 1536); \
    }

    float acc[NACC];
    #pragma unroll
    for (int k = 0; k < NACC; k++) acc[k] = 0.0f;

    STAGE(0, 0);

    #pragma unroll
    for (int u = 0; u < NTILE; u++) {
        if (u + 1 < NTILE) {
            STAGE(u + 1, (u + 1) & 1);
            WAIT_VM7();     // tile u landed; tile u+1 (7 loads) in flight
        } else {
            WAIT_VM0();
        }
        const float* base = slice + (u & 1) * BUF_F;
        #pragma unroll
        for (int u2 = 0; u2 < 4; u2++) {
            int e = lane + 64 * u2;
            float m = base[1536 + e];
            accum_elem(acc, m, base[3*e], base[3*e+1], base[3*e+2],
                       base[768 + 3*e], base[768 + 3*e+1], base[768 + 3*e+2]);
        }
        __builtin_amdgcn_sched_barrier(0);
    }

    // ---- Tail accumulate (registers loaded at kernel start) ----
    if (tid >= TAILIT) { MM.x = MM.y = MM.z = MM.w = 0.0f; }
    accum_item(acc, PA, PB, PC, TA, TB, TC, MM);

    // ---- Wave butterfly reduce (f32), cross-wave via LDS, finalize ----
    #pragma unroll
    for (int k = 0; k < NACC; k++) {
        float v = acc[k];
        #pragma unroll
        for (int o = 32; o > 0; o >>= 1) v += __shfl_xor(v, o, 64);
        acc[k] = v;
    }
    if (lane == 0) {
        #pragma unroll
        for (int k = 0; k < NACC; k++) red[w][k] = acc[k];
    }
    __syncthreads();
    if (tid == 0) {
        double a[NACC];
        #pragma unroll
        for (int k = 0; k < NACC; k++)
            a[k] = (double)red[0][k] + (double)red[1][k] +
                   (double)red[2][k] + (double)red[3][k];
        double msum = a[12] + 1e-14;
        double cost[3][3];
        #pragma unroll
        for (int i = 0; i < 3; i++)
            #pragma unroll
            for (int j = 0; j < 3; j++)
                cost[i][j] = (a[i] - a[3 + i*3 + j]) / msum;
        const int perms[6][3] = {{0,1,2},{0,2,1},{1,0,2},
                                 {1,2,0},{2,0,1},{2,1,0}};
        double best = 1e300; int bidx = 0;
        #pragma unroll
        for (int p = 0; p < 6; p++) {
            double v = (cost[0][perms[p][0]] + cost[1][perms[p][1]] +
                        cost[2][perms[p][2]]) / 3.0;
            if (v < best) { best = v; bidx = p; }
        }
        bestv[b] = best;
        out[1 + b] = (float)bidx;
    }
}

// Mean of best_val over B -> out[0].
__global__ __launch_bounds__(256) void pit_mean(
        const double* __restrict__ bestv, float* __restrict__ out) {
    __shared__ double sd[4];
    double v = 0.0;
    for (int i = threadIdx.x; i < BB; i += 256) v += bestv[i];
    int lane = threadIdx.x & 63, wave = threadIdx.x >> 6;
    #pragma unroll
    for (int o = 32; o > 0; o >>= 1) v += __shfl_down(v, o, 64);
    if (lane == 0) sd[wave] = v;
    __syncthreads();
    if (threadIdx.x == 0) {
        double s = sd[0] + sd[1] + sd[2] + sd[3];
        out[0] = (float)(s / (double)BB);
    }
}

extern "C" void kernel_launch(void* const* d_in, const int* in_sizes, int n_in,
                              void* d_out, int out_size, void* d_ws, size_t ws_size,
                              hipStream_t stream) {
    const float* pred = (const float*)d_in[0];
    const float* tgt  = (const float*)d_in[1];
    const float* mask = (const float*)d_in[2];
    float* out = (float*)d_out;
    double* bestv = (double*)d_ws;   // BB doubles

    pit_batch<<<BB, 256, 0, stream>>>(pred, tgt, mask, bestv, out);
    pit_mean<<<1, 256, 0, stream>>>(bestv, out);
}